// Round 14
// baseline (193.963 us; speedup 1.0000x reference)
//
#include <hip/hip_runtime.h>
#include <math.h>

#define D 128
#define LRELU 0.2f
#define LN_EPS 1e-5f
#define INV_LN2 1.4426950408889634f

#define NBMAX 512        // bucket table (NB = ceil(N/128) <= 512)
#define CAP 4096         // slots per bucket (mean fill ~2200)
#define P1CHUNK 8192     // edges per P1 block

typedef __attribute__((ext_vector_type(8))) short short8;
typedef __attribute__((ext_vector_type(8))) unsigned short ushort8;
typedef __attribute__((ext_vector_type(4))) float f32x4;
typedef __attribute__((ext_vector_type(2))) float f32x2;
typedef __attribute__((ext_vector_type(2))) unsigned int u32x2;

static __device__ __forceinline__ unsigned short f2bf(float f) {
    union { float f; unsigned u; } a; a.f = f;
    unsigned r = a.u + 0x7FFFu + ((a.u >> 16) & 1u);
    return (unsigned short)(r >> 16);
}

static __device__ __forceinline__ f32x2 pk_add(f32x2 a, f32x2 b) {
    f32x2 d; asm("v_pk_add_f32 %0, %1, %2" : "=v"(d) : "v"(a), "v"(b)); return d;
}
static __device__ __forceinline__ f32x2 pk_mul(f32x2 a, f32x2 b) {
    f32x2 d; asm("v_pk_mul_f32 %0, %1, %2" : "=v"(d) : "v"(a), "v"(b)); return d;
}
static __device__ __forceinline__ f32x2 pk_fma(f32x2 a, f32x2 b, f32x2 c) {
    f32x2 d; asm("v_pk_fma_f32 %0, %1, %2, %3" : "=v"(d) : "v"(a), "v"(b), "v"(c)); return d;
}
static __device__ __forceinline__ f32x2 pk_abs(f32x2 a) {
    u32x2 u = __builtin_bit_cast(u32x2, a);
    u &= 0x7FFFFFFFu;
    return __builtin_bit_cast(f32x2, u);
}
static __device__ __forceinline__ f32x2 bf2x(unsigned u) {
    f32x2 r;
    r.x = __uint_as_float(u << 16);
    r.y = __uint_as_float(u & 0xFFFF0000u);
    return r;
}

static __device__ __forceinline__ float red4_dpp(float p) {
    int v = __builtin_amdgcn_update_dpp(0, __builtin_bit_cast(int, p), 0xB1, 0xf, 0xf, true);
    p += __builtin_bit_cast(float, v);
    v = __builtin_amdgcn_update_dpp(0, __builtin_bit_cast(int, p), 0x4E, 0xf, 0xf, true);
    p += __builtin_bit_cast(float, v);
    return p;
}

// ---------------- K_prep: P1 edge-bucketing | packw ----------------

__global__ __launch_bounds__(256) void k_prep(
    const int* __restrict__ srcp, const int* __restrict__ dstp,
    int* __restrict__ bcur, unsigned* __restrict__ ebuf, int E, int N,
    const float* __restrict__ W0, const float* __restrict__ W1, const float* __restrict__ W2,
    const float* __restrict__ W3, const float* __restrict__ W4, const float* __restrict__ W5,
    ushort* __restrict__ Wp, int nP1)
{
    const int bx = blockIdx.x;
    const int tid = threadIdx.x;
    if (bx < nP1) {
        __shared__ int h[NBMAX];
        const int E2 = E + N;
        const int e0 = bx * P1CHUNK;
        const int e1 = min(e0 + P1CHUNK, E2);
        for (int t = tid; t < NBMAX; t += 256) h[t] = 0;
        __syncthreads();
        for (int e = e0 + tid; e < e1; e += 256) {
            int d = (e < E) ? dstp[e] : e - E;
            atomicAdd(&h[d >> 7], 1);
        }
        __syncthreads();
        for (int b = tid; b < NBMAX; b += 256) {
            int c = h[b];
            h[b] = c ? atomicAdd(&bcur[b], c) : 0;
        }
        __syncthreads();
        for (int e = e0 + tid; e < e1; e += 256) {
            int d  = (e < E) ? dstp[e] : e - E;
            int sc = (e < E) ? srcp[e] : e - E;
            int b = d >> 7;
            int pos = atomicAdd(&h[b], 1) & (CAP - 1);
            ebuf[(size_t)b * CAP + pos] = ((unsigned)sc << 7) | (unsigned)(d & 127);
        }
    } else {
        int bid = bx - nP1;
        int m = bid >> 6;
        int o = ((bid & 63) << 8) + tid;
        const float* W;
        if (m == 0) W = W0; else if (m == 1) W = W1; else if (m == 2) W = W2;
        else if (m == 3) W = W3; else if (m == 4) W = W4; else W = W5;
        int j  = o & 7;
        int l  = (o >> 3) & 63;
        int ct = (o >> 9) & 7;
        int kc = o >> 12;
        int k   = kc * 32 + ((l >> 4) << 3) + j;
        int col = (ct << 4) + (l & 15);
        Wp[m * 16384 + o] = f2bf(W[k * D + col]);
    }
}

// ---------------- gemm body (templated A source: fp32-direct or bf16) ----------------

template <bool AF32>
static __device__ __forceinline__ void gemm_body(
    int bxg, int seg, int tid, int N,
    const float* __restrict__ Xf, const ushort* __restrict__ Xb,
    const ushort* __restrict__ Wp,
    const float* __restrict__ bl, const float* __restrict__ br,
    ushort* __restrict__ XLb, ushort* __restrict__ XRb, float* __restrict__ RES)
{
    const int l = tid & 63;
    const int wave = tid >> 6;
    const int wr = wave >> 1, wc = wave & 1;
    const int brow = bxg * 128 + wr * 64;
    const ushort* W = Wp + seg * 16384;

    f32x4 acc[4][4] = {};
    const int arow = brow + (l & 15);
    const int koff = (l >> 4) * 8;

    #pragma unroll
    for (int kc = 0; kc < 4; ++kc) {
        short8 A[4], B[4];
        #pragma unroll
        for (int at = 0; at < 4; ++at) {
            const int r = arow + at * 16;
            if (AF32) {
                short8 av = {};
                if (r < N) {
                    const float* src = &Xf[(size_t)r * D + kc * 32 + koff];
                    float4 f0 = *(const float4*)src;
                    float4 f1 = *(const float4*)(src + 4);
                    av[0] = (short)f2bf(f0.x); av[1] = (short)f2bf(f0.y);
                    av[2] = (short)f2bf(f0.z); av[3] = (short)f2bf(f0.w);
                    av[4] = (short)f2bf(f1.x); av[5] = (short)f2bf(f1.y);
                    av[6] = (short)f2bf(f1.z); av[7] = (short)f2bf(f1.w);
                }
                A[at] = av;
            } else {
                A[at] = *(const short8*)&Xb[(size_t)r * D + kc * 32 + koff];
            }
        }
        #pragma unroll
        for (int ct = 0; ct < 4; ++ct) {
            int ctg = wc * 4 + ct;
            B[ct] = *(const short8*)&W[(((kc * 8 + ctg) * 64) + l) * 8];
        }
        #pragma unroll
        for (int at = 0; at < 4; ++at)
            #pragma unroll
            for (int ct = 0; ct < 4; ++ct)
                acc[at][ct] = __builtin_amdgcn_mfma_f32_16x16x32_bf16(A[at], B[ct], acc[at][ct], 0, 0, 0);
    }

    const int c = l & 15;
    const int r0 = (l >> 4) * 4;
    const float* bias = (seg == 0) ? bl : ((seg == 1) ? br : nullptr);
    #pragma unroll
    for (int ct = 0; ct < 4; ++ct) {
        int gcol = wc * 64 + ct * 16 + c;
        float bv = bias ? bias[gcol] : 0.f;
        #pragma unroll
        for (int at = 0; at < 4; ++at) {
            #pragma unroll
            for (int r = 0; r < 4; ++r) {
                int grow = brow + at * 16 + r0 + r;
                float v = acc[at][ct][r] + bv;
                size_t off = (size_t)grow * D + gcol;
                if (seg == 0)      XLb[off] = f2bf(v);
                else if (seg == 1) XRb[off] = f2bf(v);
                else               RES[off] = v;
            }
        }
    }
}

// ---------------- K_mid: P2b (deg+off+scatter from ebuf) | gemm0 (fp32-direct) ----------------

__global__ __launch_bounds__(256) void k_mid(
    const unsigned* __restrict__ ebuf, const int* __restrict__ bcur,
    int* __restrict__ off, int* __restrict__ csrc,
    int N, int NB, int nblk,
    const float* __restrict__ Xf, const ushort* __restrict__ Wp,
    const float* __restrict__ bl, const float* __restrict__ br,
    ushort* __restrict__ XLb, ushort* __restrict__ XRb, float* __restrict__ RES)
{
    const int bx = blockIdx.x;
    if (bx < NB) {
        const int b = bx;
        const int base = b << 7;
        const int tid = threadIdx.x;
        const int cntN = min(128, N - base);
        __shared__ int h[128];
        __shared__ int cur[128];
        __shared__ int wsum[4];
        __shared__ int wtot[2];

        // global base offset B = sum bcur[0..b)
        int acc = 0;
        for (int t = tid; t < b; t += 256) acc += bcur[t];
        #pragma unroll
        for (int o = 32; o >= 1; o >>= 1) acc += __shfl_xor(acc, o);
        if ((tid & 63) == 0) wsum[tid >> 6] = acc;
        if (tid < 128) h[tid] = 0;
        __syncthreads();
        const int B = wsum[0] + wsum[1] + wsum[2] + wsum[3];

        // pass 1 over ebuf: per-node degree histogram
        const int cnt = min(bcur[b], CAP);
        for (int k = tid; k < cnt; k += 256) {
            unsigned v = ebuf[(size_t)b * CAP + k];
            atomicAdd(&h[v & 127], 1);
        }
        __syncthreads();

        // local exclusive scan of h -> off, cur
        int dv = (tid < 128) ? h[tid] : 0;
        int incl = dv;
        if (tid < 128) {
            #pragma unroll
            for (int o = 1; o < 64; o <<= 1) {
                int u = __shfl_up(incl, o);
                if ((tid & 63) >= o) incl += u;
            }
        }
        if (tid == 63)  wtot[0] = incl;
        if (tid == 127) wtot[1] = incl;
        __syncthreads();
        if (tid < 128) {
            int add = (tid >= 64) ? wtot[0] : 0;
            int excl = B + add + incl - dv;
            cur[tid] = excl;
            if (tid < cntN) off[base + tid] = excl;
        }
        if (b == NB - 1 && tid == 0) off[N] = B + wtot[0] + wtot[1];
        __syncthreads();

        // pass 2 over ebuf: bucket-local scatter
        for (int k = tid; k < cnt; k += 256) {
            unsigned v = ebuf[(size_t)b * CAP + k];
            int p = atomicAdd(&cur[v & 127], 1);
            csrc[p] = v >> 7;
        }
    } else {
        int bid = bx - NB;
        int seg = bid / nblk;
        int bxg = bid - seg * nblk;
        gemm_body<true>(bxg, seg, threadIdx.x, N, Xf, nullptr, Wp, bl, br, XLb, XRb, RES);
    }
}

// plain gemm for layer 1 (bf16 A from Hb)
__global__ __launch_bounds__(256) void gemm_mfma(
    const ushort* __restrict__ Xb, const ushort* __restrict__ Wp, int N,
    const float* __restrict__ bl, const float* __restrict__ br,
    ushort* __restrict__ XLb, ushort* __restrict__ XRb, float* __restrict__ RES)
{
    gemm_body<false>(blockIdx.x, blockIdx.y, threadIdx.x, N, nullptr, Xb, Wp, bl, br, XLb, XRb, RES);
}

// ---------------- GATv2 aggregation + residual + LN + ReLU ----------------
// 4 nodes/wave (natural order), 16 lanes/node, lane owns 8 channels;
// packed-f32 math; 2-deep gather pipeline; exp2-domain softmax.

__global__ __launch_bounds__(256) void gat_node(
    const ushort* __restrict__ XLb, const ushort* __restrict__ XRb, const float* __restrict__ RES,
    const float* __restrict__ att, const float* __restrict__ bias,
    const float* __restrict__ g, const float* __restrict__ be,
    const int* __restrict__ off, const int* __restrict__ csrc,
    float* __restrict__ OUTf, ushort* __restrict__ OUTb)
{
    const int l = threadIdx.x & 63;
    const int i = blockIdx.x * 16 + (threadIdx.x >> 6) * 4 + (l >> 4);
    const int f = (l & 15) * 8;
    const unsigned ibase = ((unsigned)i << 7) + f;
    const int lb = l & 48;

    f32x2 at06[4], at04[4];
    #pragma unroll
    for (int k = 0; k < 4; ++k) {
        float2 a = *(const float2*)&att[f + k * 2];
        f32x2 av; av.x = a.x; av.y = a.y;
        at06[k] = av * (0.6f * INV_LN2);
        at04[k] = av * (0.4f * INV_LN2);
    }

    uint4 xru = *(const uint4*)&XRb[ibase];
    f32x2 xr2[4];
    xr2[0] = bf2x(xru.x); xr2[1] = bf2x(xru.y); xr2[2] = bf2x(xru.z); xr2[3] = bf2x(xru.w);

    const int e0 = off[i], e1 = off[i + 1];
    const int len = e1 - e0;
    int mx = max(len, __shfl_xor(len, 16));
    mx = max(mx, __shfl_xor(mx, 32));

    float m = -1e30f, s = 0.f;
    f32x2 a2[4] = {};

    for (int c0 = 0; c0 < mx; c0 += 16) {
        int myj = csrc[min(e0 + c0 + (l & 15), e1 - 1)];
        const int rem = mx - c0;
        const int nbb = min(4, (rem + 3) >> 2);
        const int kleft = len - c0;

        uint4 u_[4];
        {
            int s0 = __shfl(myj, lb + 0);
            int s1 = __shfl(myj, lb + 1);
            int s2 = __shfl(myj, lb + 2);
            int s3 = __shfl(myj, lb + 3);
            u_[0] = *(const uint4*)&XLb[((unsigned)s0 << 7) + f];
            u_[1] = *(const uint4*)&XLb[((unsigned)s1 << 7) + f];
            u_[2] = *(const uint4*)&XLb[((unsigned)s2 << 7) + f];
            u_[3] = *(const uint4*)&XLb[((unsigned)s3 << 7) + f];
        }

        #pragma unroll
        for (int bb = 0; bb < 4; ++bb) {
            if (bb >= nbb) break;
            uint4 uc[4];
            #pragma unroll
            for (int j = 0; j < 4; ++j) uc[j] = u_[j];
            if (bb + 1 < nbb) {
                int s0 = __shfl(myj, lb + (bb + 1) * 4 + 0);
                int s1 = __shfl(myj, lb + (bb + 1) * 4 + 1);
                int s2 = __shfl(myj, lb + (bb + 1) * 4 + 2);
                int s3 = __shfl(myj, lb + (bb + 1) * 4 + 3);
                u_[0] = *(const uint4*)&XLb[((unsigned)s0 << 7) + f];
                u_[1] = *(const uint4*)&XLb[((unsigned)s1 << 7) + f];
                u_[2] = *(const uint4*)&XLb[((unsigned)s2 << 7) + f];
                u_[3] = *(const uint4*)&XLb[((unsigned)s3 << 7) + f];
            }

            const int kb = kleft - bb * 4;
            f32x2 xp[4][4];
            float p[4];
            #pragma unroll
            for (int j = 0; j < 4; ++j) {
                xp[j][0] = bf2x(uc[j].x);
                xp[j][1] = bf2x(uc[j].y);
                xp[j][2] = bf2x(uc[j].z);
                xp[j][3] = bf2x(uc[j].w);
                f32x2 v0 = pk_add(xp[j][0], xr2[0]);
                f32x2 pj2 = pk_mul(v0, at06[0]);
                pj2 = pk_fma(pk_abs(v0), at04[0], pj2);
                #pragma unroll
                for (int k = 1; k < 4; ++k) {
                    f32x2 v = pk_add(xp[j][k], xr2[k]);
                    pj2 = pk_fma(v, at06[k], pj2);
                    pj2 = pk_fma(pk_abs(v), at04[k], pj2);
                }
                float pj = pj2.x + pj2.y;
                pj = red4_dpp(pj);
                p[j] = (j < kb) ? pj : -1e30f;
            }
            float pmax = fmaxf(fmaxf(p[0], p[1]), fmaxf(p[2], p[3]));
            float nm = fmaxf(m, pmax);
            float so = exp2f(m - nm);
            float w0 = exp2f(p[0] - nm), w1 = exp2f(p[1] - nm);
            float w2 = exp2f(p[2] - nm), w3 = exp2f(p[3] - nm);
            s = s * so + ((w0 + w1) + (w2 + w3));
            f32x2 so2; so2.x = so; so2.y = so;
            f32x2 w02; w02.x = w0; w02.y = w0;
            f32x2 w12; w12.x = w1; w12.y = w1;
            f32x2 w22; w22.x = w2; w22.y = w2;
            f32x2 w32; w32.x = w3; w32.y = w3;
            #pragma unroll
            for (int k = 0; k < 4; ++k) {
                f32x2 t = pk_mul(xp[0][k], w02);
                t = pk_fma(xp[1][k], w12, t);
                t = pk_fma(xp[2][k], w22, t);
                t = pk_fma(xp[3][k], w32, t);
                a2[k] = pk_fma(a2[k], so2, t);
            }
            m = nm;
        }
    }

    const float4 rsA = *(const float4*)&RES[ibase];
    const float4 rsB = *(const float4*)&RES[ibase + 4];
    const float4 biA = *(const float4*)&bias[f];
    const float4 biB = *(const float4*)&bias[f + 4];
    float inv = 1.f / s;
    float r0 = a2[0].x * inv + rsA.x + biA.x;
    float r1 = a2[0].y * inv + rsA.y + biA.y;
    float r2 = a2[1].x * inv + rsA.z + biA.z;
    float r3 = a2[1].y * inv + rsA.w + biA.w;
    float r4 = a2[2].x * inv + rsB.x + biB.x;
    float r5 = a2[2].y * inv + rsB.y + biB.y;
    float r6 = a2[3].x * inv + rsB.z + biB.z;
    float r7 = a2[3].y * inv + rsB.w + biB.w;

    float sum = ((r0 + r1) + (r2 + r3)) + ((r4 + r5) + (r6 + r7));
    float sq  = ((r0 * r0 + r1 * r1) + (r2 * r2 + r3 * r3))
              + ((r4 * r4 + r5 * r5) + (r6 * r6 + r7 * r7));
    #pragma unroll
    for (int o = 8; o >= 1; o >>= 1) {
        sum += __shfl_xor(sum, o);
        sq  += __shfl_xor(sq, o);
    }
    float mu  = sum * (1.f / 128.f);
    float var = sq * (1.f / 128.f) - mu * mu;
    float isd = rsqrtf(var + LN_EPS);
    const float4 gvA = *(const float4*)&g[f];
    const float4 gvB = *(const float4*)&g[f + 4];
    const float4 bvA = *(const float4*)&be[f];
    const float4 bvB = *(const float4*)&be[f + 4];
    float o0 = fmaxf((r0 - mu) * isd * gvA.x + bvA.x, 0.f);
    float o1 = fmaxf((r1 - mu) * isd * gvA.y + bvA.y, 0.f);
    float o2 = fmaxf((r2 - mu) * isd * gvA.z + bvA.z, 0.f);
    float o3 = fmaxf((r3 - mu) * isd * gvA.w + bvA.w, 0.f);
    float o4 = fmaxf((r4 - mu) * isd * gvB.x + bvB.x, 0.f);
    float o5 = fmaxf((r5 - mu) * isd * gvB.y + bvB.y, 0.f);
    float o6 = fmaxf((r6 - mu) * isd * gvB.z + bvB.z, 0.f);
    float o7 = fmaxf((r7 - mu) * isd * gvB.w + bvB.w, 0.f);

    if (OUTb) {
        ushort8 ob;
        ob[0] = f2bf(o0); ob[1] = f2bf(o1); ob[2] = f2bf(o2); ob[3] = f2bf(o3);
        ob[4] = f2bf(o4); ob[5] = f2bf(o5); ob[6] = f2bf(o6); ob[7] = f2bf(o7);
        *(ushort8*)&OUTb[ibase] = ob;
    } else {
        *(float4*)&OUTf[ibase]     = make_float4(o0, o1, o2, o3);
        *(float4*)&OUTf[ibase + 4] = make_float4(o4, o5, o6, o7);
    }
}

// ---------------- launch ----------------

extern "C" void kernel_launch(void* const* d_in, const int* in_sizes, int n_in,
                              void* d_out, int out_size, void* d_ws, size_t ws_size,
                              hipStream_t stream)
{
    const float* x    = (const float*)d_in[0];
    const int*   ei   = (const int*)d_in[1];
    const float* Wl0  = (const float*)d_in[2];
    const float* bl0  = (const float*)d_in[3];
    const float* Wr0  = (const float*)d_in[4];
    const float* br0  = (const float*)d_in[5];
    const float* att0 = (const float*)d_in[6];
    const float* Wres0= (const float*)d_in[7];
    const float* bias0= (const float*)d_in[8];
    const float* g0   = (const float*)d_in[9];
    const float* be0  = (const float*)d_in[10];
    const float* Wl1  = (const float*)d_in[11];
    const float* bl1  = (const float*)d_in[12];
    const float* br1  = (const float*)d_in[14];
    const float* Wr1  = (const float*)d_in[13];
    const float* att1 = (const float*)d_in[15];
    const float* Wres1= (const float*)d_in[16];
    const float* bias1= (const float*)d_in[17];
    const float* g1   = (const float*)d_in[18];
    const float* be1  = (const float*)d_in[19];

    const int N  = in_sizes[0] / D;
    const int E  = in_sizes[1] / 2;
    const int E2 = E + N;
    const int nblk = (N + 127) / 128;   // = NB buckets
    const int Mp = nblk * 128;
    const int NB = nblk;

    char* w = (char*)d_ws;
    ushort* Hb  = (ushort*)w; w += (size_t)Mp * D * 2;
    ushort* XLb = (ushort*)w; w += (size_t)Mp * D * 2;
    ushort* XRb = (ushort*)w; w += (size_t)Mp * D * 2;
    float*  RES = (float*)w;  w += (size_t)Mp * D * 4;
    ushort* Wp  = (ushort*)w; w += (size_t)6 * 16384 * 2;
    int* off     = (int*)w; w += (size_t)(N + 1) * 4;
    int* bcur    = (int*)w; w += (size_t)NBMAX * 4;
    unsigned* ebuf = (unsigned*)w; w += (size_t)NB * CAP * 4;
    int* csrc    = (int*)w; w += (size_t)E2 * 4;

    const int* srcp = ei;
    const int* dstp = ei + E;

    const int nP1 = (E2 + P1CHUNK - 1) / P1CHUNK;
    const int nPW = 6 * 64;
    const int nGM = nblk * 3;

    hipMemsetAsync(bcur, 0, (size_t)NBMAX * 4, stream);
    k_prep<<<nP1 + nPW, 256, 0, stream>>>(srcp, dstp, bcur, ebuf, E, N,
                                          Wl0, Wr0, Wres0, Wl1, Wr1, Wres1,
                                          Wp, nP1);

    // P2b (deg+off+scatter) + gemm layer-0 (fp32-direct) fused
    k_mid<<<NB + nGM, 256, 0, stream>>>(ebuf, bcur, off, csrc, N, NB, nblk,
                                        x, Wp, bl0, br0, XLb, XRb, RES);

    const int gatg = N / 16;
    dim3 ggrid(nblk, 3);

    gat_node<<<gatg, 256, 0, stream>>>(XLb, XRb, RES, att0, bias0, g0, be0, off, csrc, nullptr, Hb);
    gemm_mfma<<<ggrid, 256, 0, stream>>>(Hb, Wp + 3 * 16384, N, bl1, br1, XLb, XRb, RES);
    gat_node<<<gatg, 256, 0, stream>>>(XLb, XRb, RES, att1, bias1, g1, be1, off, csrc, (float*)d_out, nullptr);
}

// Round 16
// 186.353 us; speedup vs baseline: 1.0408x; 1.0408x over previous
//
#include <hip/hip_runtime.h>
#include <math.h>

#define D 128
#define LRELU 0.2f
#define LN_EPS 1e-5f
#define INV_LN2 1.4426950408889634f

#define NBMAX 512        // bucket table (NB = ceil(N/128) <= 512)
#define CAP 4096         // slots per bucket (mean fill ~2200)
#define P1CHUNK 8192     // edges per P1 block

typedef __attribute__((ext_vector_type(8))) short short8;
typedef __attribute__((ext_vector_type(8))) unsigned short ushort8;
typedef __attribute__((ext_vector_type(4))) float f32x4;
typedef __attribute__((ext_vector_type(2))) float f32x2;
typedef __attribute__((ext_vector_type(2))) unsigned int u32x2;
typedef __attribute__((ext_vector_type(4))) unsigned int u32x4;

static __device__ __forceinline__ unsigned short f2bf(float f) {
    union { float f; unsigned u; } a; a.f = f;
    unsigned r = a.u + 0x7FFFu + ((a.u >> 16) & 1u);
    return (unsigned short)(r >> 16);
}

static __device__ __forceinline__ f32x2 pk_add(f32x2 a, f32x2 b) {
    f32x2 d; asm("v_pk_add_f32 %0, %1, %2" : "=v"(d) : "v"(a), "v"(b)); return d;
}
static __device__ __forceinline__ f32x2 pk_mul(f32x2 a, f32x2 b) {
    f32x2 d; asm("v_pk_mul_f32 %0, %1, %2" : "=v"(d) : "v"(a), "v"(b)); return d;
}
static __device__ __forceinline__ f32x2 pk_fma(f32x2 a, f32x2 b, f32x2 c) {
    f32x2 d; asm("v_pk_fma_f32 %0, %1, %2, %3" : "=v"(d) : "v"(a), "v"(b), "v"(c)); return d;
}
static __device__ __forceinline__ f32x2 pk_abs(f32x2 a) {
    u32x2 u = __builtin_bit_cast(u32x2, a);
    u &= 0x7FFFFFFFu;
    return __builtin_bit_cast(f32x2, u);
}
static __device__ __forceinline__ f32x2 bf2x(unsigned u) {
    f32x2 r;
    r.x = __uint_as_float(u << 16);
    r.y = __uint_as_float(u & 0xFFFF0000u);
    return r;
}

static __device__ __forceinline__ float red4_dpp(float p) {
    int v = __builtin_amdgcn_update_dpp(0, __builtin_bit_cast(int, p), 0xB1, 0xf, 0xf, true);
    p += __builtin_bit_cast(float, v);
    v = __builtin_amdgcn_update_dpp(0, __builtin_bit_cast(int, p), 0x4E, 0xf, 0xf, true);
    p += __builtin_bit_cast(float, v);
    return p;
}

#define SCB 256

// ---------------- K_prep: P1 edge-bucketing | convx | packw ----------------

__global__ __launch_bounds__(256) void k_prep(
    const int* __restrict__ srcp, const int* __restrict__ dstp,
    int* __restrict__ bcur, unsigned* __restrict__ ebuf, int E, int N,
    const float* __restrict__ X, ushort* __restrict__ Xb, int Mp,
    const float* __restrict__ W0, const float* __restrict__ W1, const float* __restrict__ W2,
    const float* __restrict__ W3, const float* __restrict__ W4, const float* __restrict__ W5,
    ushort* __restrict__ Wp, int nP1, int nCV)
{
    const int bx = blockIdx.x;
    const int tid = threadIdx.x;
    if (bx < nP1) {
        __shared__ int h[NBMAX];
        const int E2 = E + N;
        const int e0 = bx * P1CHUNK;
        const int e1 = min(e0 + P1CHUNK, E2);
        for (int t = tid; t < NBMAX; t += 256) h[t] = 0;
        __syncthreads();
        for (int e = e0 + tid; e < e1; e += 256) {
            int d = (e < E) ? dstp[e] : e - E;
            atomicAdd(&h[d >> 7], 1);
        }
        __syncthreads();
        for (int b = tid; b < NBMAX; b += 256) {
            int c = h[b];
            h[b] = c ? atomicAdd(&bcur[b], c) : 0;
        }
        __syncthreads();
        for (int e = e0 + tid; e < e1; e += 256) {
            int d  = (e < E) ? dstp[e] : e - E;
            int sc = (e < E) ? srcp[e] : e - E;
            int b = d >> 7;
            int pos = atomicAdd(&h[b], 1) & (CAP - 1);
            ebuf[(size_t)b * CAP + pos] = ((unsigned)sc << 7) | (unsigned)(d & 127);
        }
    } else if (bx < nP1 + nCV) {
        int idx = (bx - nP1) * 256 + tid;
        if (idx >= Mp * (D / 4)) return;
        ushort4 o;
        if (idx < N * (D / 4)) {
            float4 v = ((const float4*)X)[idx];
            o.x = f2bf(v.x); o.y = f2bf(v.y); o.z = f2bf(v.z); o.w = f2bf(v.w);
        } else {
            o = make_ushort4(0, 0, 0, 0);
        }
        ((ushort4*)Xb)[idx] = o;
    } else {
        int bid = bx - nP1 - nCV;
        int m = bid >> 6;
        int o = ((bid & 63) << 8) + tid;
        const float* W;
        if (m == 0) W = W0; else if (m == 1) W = W1; else if (m == 2) W = W2;
        else if (m == 3) W = W3; else if (m == 4) W = W4; else W = W5;
        int j  = o & 7;
        int l  = (o >> 3) & 63;
        int ct = (o >> 9) & 7;
        int kc = o >> 12;
        int k   = kc * 32 + ((l >> 4) << 3) + j;
        int col = (ct << 4) + (l & 15);
        Wp[m * 16384 + o] = f2bf(W[k * D + col]);
    }
}

// ---------------- P2a: per-bucket histogram -> deg (coalesced) + bucket totals ----------------

__global__ __launch_bounds__(256) void bhist_kernel(const unsigned* __restrict__ ebuf,
                                                    const int* __restrict__ bcur,
                                                    int* __restrict__ deg,
                                                    int* __restrict__ btot, int N) {
    const int b = blockIdx.x;
    const int base = b << 7;
    const int tid = threadIdx.x;
    __shared__ int h[128];
    __shared__ int t2[2];
    if (tid < 128) h[tid] = 0;
    __syncthreads();
    const int cnt = min(bcur[b], CAP);
    for (int k = tid; k < cnt; k += 256) {
        unsigned v = ebuf[(size_t)b * CAP + k];
        atomicAdd(&h[v & 127], 1);
    }
    __syncthreads();
    int v = (tid < 128) ? h[tid] : 0;
    if (tid < 128 && base + tid < N) deg[base + tid] = v;
    #pragma unroll
    for (int o = 32; o >= 1; o >>= 1) v += __shfl_xor(v, o);
    if (tid == 0)  t2[0] = v;
    if (tid == 64) t2[1] = v;
    __syncthreads();
    if (tid == 0) btot[b] = t2[0] + t2[1];
}

// ---------------- gemm body (bf16 A) ----------------

static __device__ __forceinline__ void gemm_body(
    int bxg, int seg, int tid,
    const ushort* __restrict__ Xb, const ushort* __restrict__ Wp,
    const float* __restrict__ bl, const float* __restrict__ br,
    ushort* __restrict__ XLb, ushort* __restrict__ XRb, float* __restrict__ RES)
{
    const int l = tid & 63;
    const int wave = tid >> 6;
    const int wr = wave >> 1, wc = wave & 1;
    const int brow = bxg * 128 + wr * 64;
    const ushort* W = Wp + seg * 16384;

    f32x4 acc[4][4] = {};
    const int arow = brow + (l & 15);
    const int koff = (l >> 4) * 8;

    #pragma unroll
    for (int kc = 0; kc < 4; ++kc) {
        short8 A[4], B[4];
        #pragma unroll
        for (int at = 0; at < 4; ++at)
            A[at] = *(const short8*)&Xb[(size_t)(arow + at * 16) * D + kc * 32 + koff];
        #pragma unroll
        for (int ct = 0; ct < 4; ++ct) {
            int ctg = wc * 4 + ct;
            B[ct] = *(const short8*)&W[(((kc * 8 + ctg) * 64) + l) * 8];
        }
        #pragma unroll
        for (int at = 0; at < 4; ++at)
            #pragma unroll
            for (int ct = 0; ct < 4; ++ct)
                acc[at][ct] = __builtin_amdgcn_mfma_f32_16x16x32_bf16(A[at], B[ct], acc[at][ct], 0, 0, 0);
    }

    const int c = l & 15;
    const int r0 = (l >> 4) * 4;
    const float* bias = (seg == 0) ? bl : ((seg == 1) ? br : nullptr);
    #pragma unroll
    for (int ct = 0; ct < 4; ++ct) {
        int gcol = wc * 64 + ct * 16 + c;
        float bv = bias ? bias[gcol] : 0.f;
        #pragma unroll
        for (int at = 0; at < 4; ++at) {
            #pragma unroll
            for (int r = 0; r < 4; ++r) {
                int grow = brow + at * 16 + r0 + r;
                float v = acc[at][ct][r] + bv;
                size_t off = (size_t)grow * D + gcol;
                if (seg == 0)      XLb[off] = f2bf(v);
                else if (seg == 1) XRb[off] = f2bf(v);
                else               RES[off] = v;
            }
        }
    }
}

// ---------------- K_mid: P2b (off-from-btot + bucket-local scatter) | gemm0 ----------------

__global__ __launch_bounds__(256) void k_mid(
    const unsigned* __restrict__ ebuf, const int* __restrict__ bcur,
    const int* __restrict__ deg, const int* __restrict__ btot,
    int* __restrict__ off, int* __restrict__ csrc, int N, int NB, int nblk,
    const ushort* __restrict__ Xb, const ushort* __restrict__ Wp,
    const float* __restrict__ bl, const float* __restrict__ br,
    ushort* __restrict__ XLb, ushort* __restrict__ XRb, float* __restrict__ RES)
{
    const int bx = blockIdx.x;
    if (bx < NB) {
        const int b = bx;
        const int base = b << 7;
        const int tid = threadIdx.x;
        __shared__ int cur[128];
        __shared__ int wsum[4];
        __shared__ int wtot[2];

        // global base offset B = sum btot[0..b)
        int acc = 0;
        for (int t = tid; t < b; t += 256) acc += btot[t];
        #pragma unroll
        for (int o = 32; o >= 1; o >>= 1) acc += __shfl_xor(acc, o);
        if ((tid & 63) == 0) wsum[tid >> 6] = acc;
        __syncthreads();
        const int B = wsum[0] + wsum[1] + wsum[2] + wsum[3];

        // local exclusive scan of deg[base..base+127]
        int dv = 0;
        if (tid < 128 && base + tid < N) dv = deg[base + tid];
        int incl = dv;
        if (tid < 128) {
            #pragma unroll
            for (int o = 1; o < 64; o <<= 1) {
                int u = __shfl_up(incl, o);
                if ((tid & 63) >= o) incl += u;
            }
        }
        if (tid == 63)  wtot[0] = incl;
        if (tid == 127) wtot[1] = incl;
        __syncthreads();
        if (tid < 128) {
            int add = (tid >= 64) ? wtot[0] : 0;
            int excl = B + add + incl - dv;
            cur[tid] = excl;
            if (base + tid < N) off[base + tid] = excl;
        }
        if (b == NB - 1 && tid == 0) off[N] = B + wtot[0] + wtot[1];
        __syncthreads();

        // bucket-local scatter
        const int cnt = min(bcur[b], CAP);
        for (int k = tid; k < cnt; k += 256) {
            unsigned v = ebuf[(size_t)b * CAP + k];
            int p = atomicAdd(&cur[v & 127], 1);
            csrc[p] = v >> 7;
        }
    } else {
        int bid = bx - NB;
        int seg = bid / nblk;
        int bxg = bid - seg * nblk;
        gemm_body(bxg, seg, threadIdx.x, Xb, Wp, bl, br, XLb, XRb, RES);
    }
}

__global__ __launch_bounds__(256) void gemm_mfma(
    const ushort* __restrict__ Xb, const ushort* __restrict__ Wp,
    const float* __restrict__ bl, const float* __restrict__ br,
    ushort* __restrict__ XLb, ushort* __restrict__ XRb, float* __restrict__ RES)
{
    gemm_body(blockIdx.x, blockIdx.y, threadIdx.x, Xb, Wp, bl, br, XLb, XRb, RES);
}

// ---------------- GATv2 aggregation + residual + LN + ReLU ----------------
// 4 nodes/wave (natural order), 16 lanes/node, lane owns 8 channels;
// packed-f32 math; 2-deep gather pipeline; NT hints on streamed operands.

__global__ __launch_bounds__(256) void gat_node(
    const ushort* __restrict__ XLb, const ushort* __restrict__ XRb, const float* __restrict__ RES,
    const float* __restrict__ att, const float* __restrict__ bias,
    const float* __restrict__ g, const float* __restrict__ be,
    const int* __restrict__ off, const int* __restrict__ csrc,
    float* __restrict__ OUTf, ushort* __restrict__ OUTb)
{
    const int l = threadIdx.x & 63;
    const int i = blockIdx.x * 16 + (threadIdx.x >> 6) * 4 + (l >> 4);
    const int f = (l & 15) * 8;
    const unsigned ibase = ((unsigned)i << 7) + f;
    const int lb = l & 48;

    f32x2 at06[4], at04[4];
    #pragma unroll
    for (int k = 0; k < 4; ++k) {
        float2 a = *(const float2*)&att[f + k * 2];
        f32x2 av; av.x = a.x; av.y = a.y;
        at06[k] = av * (0.6f * INV_LN2);
        at04[k] = av * (0.4f * INV_LN2);
    }

    u32x4 xru = __builtin_nontemporal_load((const u32x4*)&XRb[ibase]);
    f32x2 xr2[4];
    xr2[0] = bf2x(xru.x); xr2[1] = bf2x(xru.y); xr2[2] = bf2x(xru.z); xr2[3] = bf2x(xru.w);

    const int e0 = off[i], e1 = off[i + 1];
    const int len = e1 - e0;
    int mx = max(len, __shfl_xor(len, 16));
    mx = max(mx, __shfl_xor(mx, 32));

    float m = -1e30f, s = 0.f;
    f32x2 a2[4] = {};

    for (int c0 = 0; c0 < mx; c0 += 16) {
        int myj = __builtin_nontemporal_load(&csrc[min(e0 + c0 + (l & 15), e1 - 1)]);
        const int rem = mx - c0;
        const int nbb = min(4, (rem + 3) >> 2);
        const int kleft = len - c0;

        u32x4 u_[4];
        {
            int s0 = __shfl(myj, lb + 0);
            int s1 = __shfl(myj, lb + 1);
            int s2 = __shfl(myj, lb + 2);
            int s3 = __shfl(myj, lb + 3);
            u_[0] = *(const u32x4*)&XLb[((unsigned)s0 << 7) + f];
            u_[1] = *(const u32x4*)&XLb[((unsigned)s1 << 7) + f];
            u_[2] = *(const u32x4*)&XLb[((unsigned)s2 << 7) + f];
            u_[3] = *(const u32x4*)&XLb[((unsigned)s3 << 7) + f];
        }

        #pragma unroll
        for (int bb = 0; bb < 4; ++bb) {
            if (bb >= nbb) break;
            u32x4 uc[4];
            #pragma unroll
            for (int j = 0; j < 4; ++j) uc[j] = u_[j];
            if (bb + 1 < nbb) {
                int s0 = __shfl(myj, lb + (bb + 1) * 4 + 0);
                int s1 = __shfl(myj, lb + (bb + 1) * 4 + 1);
                int s2 = __shfl(myj, lb + (bb + 1) * 4 + 2);
                int s3 = __shfl(myj, lb + (bb + 1) * 4 + 3);
                u_[0] = *(const u32x4*)&XLb[((unsigned)s0 << 7) + f];
                u_[1] = *(const u32x4*)&XLb[((unsigned)s1 << 7) + f];
                u_[2] = *(const u32x4*)&XLb[((unsigned)s2 << 7) + f];
                u_[3] = *(const u32x4*)&XLb[((unsigned)s3 << 7) + f];
            }

            const int kb = kleft - bb * 4;
            f32x2 xp[4][4];
            float p[4];
            #pragma unroll
            for (int j = 0; j < 4; ++j) {
                xp[j][0] = bf2x(uc[j].x);
                xp[j][1] = bf2x(uc[j].y);
                xp[j][2] = bf2x(uc[j].z);
                xp[j][3] = bf2x(uc[j].w);
                f32x2 v0 = pk_add(xp[j][0], xr2[0]);
                f32x2 pj2 = pk_mul(v0, at06[0]);
                pj2 = pk_fma(pk_abs(v0), at04[0], pj2);
                #pragma unroll
                for (int k = 1; k < 4; ++k) {
                    f32x2 v = pk_add(xp[j][k], xr2[k]);
                    pj2 = pk_fma(v, at06[k], pj2);
                    pj2 = pk_fma(pk_abs(v), at04[k], pj2);
                }
                float pj = pj2.x + pj2.y;
                pj = red4_dpp(pj);
                p[j] = (j < kb) ? pj : -1e30f;
            }
            float pmax = fmaxf(fmaxf(p[0], p[1]), fmaxf(p[2], p[3]));
            float nm = fmaxf(m, pmax);
            float so = exp2f(m - nm);
            float w0 = exp2f(p[0] - nm), w1 = exp2f(p[1] - nm);
            float w2 = exp2f(p[2] - nm), w3 = exp2f(p[3] - nm);
            s = s * so + ((w0 + w1) + (w2 + w3));
            f32x2 so2; so2.x = so; so2.y = so;
            f32x2 w02; w02.x = w0; w02.y = w0;
            f32x2 w12; w12.x = w1; w12.y = w1;
            f32x2 w22; w22.x = w2; w22.y = w2;
            f32x2 w32; w32.x = w3; w32.y = w3;
            #pragma unroll
            for (int k = 0; k < 4; ++k) {
                f32x2 t = pk_mul(xp[0][k], w02);
                t = pk_fma(xp[1][k], w12, t);
                t = pk_fma(xp[2][k], w22, t);
                t = pk_fma(xp[3][k], w32, t);
                a2[k] = pk_fma(a2[k], so2, t);
            }
            m = nm;
        }
    }

    const f32x4 rsA = __builtin_nontemporal_load((const f32x4*)&RES[ibase]);
    const f32x4 rsB = __builtin_nontemporal_load((const f32x4*)&RES[ibase + 4]);
    const float4 biA = *(const float4*)&bias[f];
    const float4 biB = *(const float4*)&bias[f + 4];
    float inv = 1.f / s;
    float r0 = a2[0].x * inv + rsA.x + biA.x;
    float r1 = a2[0].y * inv + rsA.y + biA.y;
    float r2 = a2[1].x * inv + rsA.z + biA.z;
    float r3 = a2[1].y * inv + rsA.w + biA.w;
    float r4 = a2[2].x * inv + rsB.x + biB.x;
    float r5 = a2[2].y * inv + rsB.y + biB.y;
    float r6 = a2[3].x * inv + rsB.z + biB.z;
    float r7 = a2[3].y * inv + rsB.w + biB.w;

    float sum = ((r0 + r1) + (r2 + r3)) + ((r4 + r5) + (r6 + r7));
    float sq  = ((r0 * r0 + r1 * r1) + (r2 * r2 + r3 * r3))
              + ((r4 * r4 + r5 * r5) + (r6 * r6 + r7 * r7));
    #pragma unroll
    for (int o = 8; o >= 1; o >>= 1) {
        sum += __shfl_xor(sum, o);
        sq  += __shfl_xor(sq, o);
    }
    float mu  = sum * (1.f / 128.f);
    float var = sq * (1.f / 128.f) - mu * mu;
    float isd = rsqrtf(var + LN_EPS);
    const float4 gvA = *(const float4*)&g[f];
    const float4 gvB = *(const float4*)&g[f + 4];
    const float4 bvA = *(const float4*)&be[f];
    const float4 bvB = *(const float4*)&be[f + 4];
    float o0 = fmaxf((r0 - mu) * isd * gvA.x + bvA.x, 0.f);
    float o1 = fmaxf((r1 - mu) * isd * gvA.y + bvA.y, 0.f);
    float o2 = fmaxf((r2 - mu) * isd * gvA.z + bvA.z, 0.f);
    float o3 = fmaxf((r3 - mu) * isd * gvA.w + bvA.w, 0.f);
    float o4 = fmaxf((r4 - mu) * isd * gvB.x + bvB.x, 0.f);
    float o5 = fmaxf((r5 - mu) * isd * gvB.y + bvB.y, 0.f);
    float o6 = fmaxf((r6 - mu) * isd * gvB.z + bvB.z, 0.f);
    float o7 = fmaxf((r7 - mu) * isd * gvB.w + bvB.w, 0.f);

    if (OUTb) {
        ushort8 ob;
        ob[0] = f2bf(o0); ob[1] = f2bf(o1); ob[2] = f2bf(o2); ob[3] = f2bf(o3);
        ob[4] = f2bf(o4); ob[5] = f2bf(o5); ob[6] = f2bf(o6); ob[7] = f2bf(o7);
        __builtin_nontemporal_store(ob, (ushort8*)&OUTb[ibase]);
    } else {
        f32x4 oA; oA.x = o0; oA.y = o1; oA.z = o2; oA.w = o3;
        f32x4 oB; oB.x = o4; oB.y = o5; oB.z = o6; oB.w = o7;
        __builtin_nontemporal_store(oA, (f32x4*)&OUTf[ibase]);
        __builtin_nontemporal_store(oB, (f32x4*)&OUTf[ibase + 4]);
    }
}

// ---------------- launch ----------------

extern "C" void kernel_launch(void* const* d_in, const int* in_sizes, int n_in,
                              void* d_out, int out_size, void* d_ws, size_t ws_size,
                              hipStream_t stream)
{
    const float* x    = (const float*)d_in[0];
    const int*   ei   = (const int*)d_in[1];
    const float* Wl0  = (const float*)d_in[2];
    const float* bl0  = (const float*)d_in[3];
    const float* Wr0  = (const float*)d_in[4];
    const float* br0  = (const float*)d_in[5];
    const float* att0 = (const float*)d_in[6];
    const float* Wres0= (const float*)d_in[7];
    const float* bias0= (const float*)d_in[8];
    const float* g0   = (const float*)d_in[9];
    const float* be0  = (const float*)d_in[10];
    const float* Wl1  = (const float*)d_in[11];
    const float* bl1  = (const float*)d_in[12];
    const float* Wr1  = (const float*)d_in[13];
    const float* br1  = (const float*)d_in[14];
    const float* att1 = (const float*)d_in[15];
    const float* Wres1= (const float*)d_in[16];
    const float* bias1= (const float*)d_in[17];
    const float* g1   = (const float*)d_in[18];
    const float* be1  = (const float*)d_in[19];

    const int N  = in_sizes[0] / D;
    const int E  = in_sizes[1] / 2;
    const int E2 = E + N;
    const int nblk = (N + 127) / 128;   // = NB buckets
    const int Mp = nblk * 128;
    const int NB = nblk;

    char* w = (char*)d_ws;
    ushort* Xb  = (ushort*)w; w += (size_t)Mp * D * 2;
    ushort* Hb  = (ushort*)w; w += (size_t)Mp * D * 2;
    ushort* XLb = (ushort*)w; w += (size_t)Mp * D * 2;
    ushort* XRb = (ushort*)w; w += (size_t)Mp * D * 2;
    float*  RES = (float*)w;  w += (size_t)Mp * D * 4;
    ushort* Wp  = (ushort*)w; w += (size_t)6 * 16384 * 2;
    int* deg     = (int*)w; w += (size_t)N * 4;
    int* off     = (int*)w; w += (size_t)(N + 1) * 4;
    int* bcur    = (int*)w; w += (size_t)NBMAX * 4;
    int* btot    = (int*)w; w += (size_t)NBMAX * 4;
    unsigned* ebuf = (unsigned*)w; w += (size_t)NB * CAP * 4;
    int* csrc    = (int*)w; w += (size_t)E2 * 4;

    const int* srcp = ei;
    const int* dstp = ei + E;

    const int nP1 = (E2 + P1CHUNK - 1) / P1CHUNK;
    const int nCV = (Mp * (D / 4) + 255) / 256;
    const int nPW = 6 * 64;
    const int nGM = nblk * 3;

    hipMemsetAsync(bcur, 0, (size_t)NBMAX * 4, stream);
    k_prep<<<nP1 + nCV + nPW, 256, 0, stream>>>(srcp, dstp, bcur, ebuf, E, N,
                                                x, Xb, Mp,
                                                Wl0, Wr0, Wres0, Wl1, Wr1, Wres1,
                                                Wp, nP1, nCV);
    bhist_kernel<<<NB, 256, 0, stream>>>(ebuf, bcur, deg, btot, N);

    // P2b (off + scatter) + gemm layer-0 fused
    k_mid<<<NB + nGM, 256, 0, stream>>>(ebuf, bcur, deg, btot, off, csrc, N, NB, nblk,
                                        Xb, Wp, bl0, br0, XLb, XRb, RES);

    const int gatg = N / 16;
    dim3 ggrid(nblk, 3);

    gat_node<<<gatg, 256, 0, stream>>>(XLb, XRb, RES, att0, bias0, g0, be0, off, csrc, nullptr, Hb);
    gemm_mfma<<<ggrid, 256, 0, stream>>>(Hb, Wp + 3 * 16384, bl1, br1, XLb, XRb, RES);
    gat_node<<<gatg, 256, 0, stream>>>(XLb, XRb, RES, att1, bias1, g1, be1, off, csrc, (float*)d_out, nullptr);
}

// Round 17
// 185.144 us; speedup vs baseline: 1.0476x; 1.0065x over previous
//
#include <hip/hip_runtime.h>
#include <math.h>

#define D 128
#define LRELU 0.2f
#define LN_EPS 1e-5f
#define INV_LN2 1.4426950408889634f

#define NBMAX 512        // bucket table (NB = ceil(N/128) <= 512)
#define CAP 4096         // slots per bucket (mean fill ~2200)
#define P1CHUNK 8192     // edges per P1 block

typedef __attribute__((ext_vector_type(8))) short short8;
typedef __attribute__((ext_vector_type(8))) unsigned short ushort8;
typedef __attribute__((ext_vector_type(4))) float f32x4;
typedef __attribute__((ext_vector_type(2))) float f32x2;
typedef __attribute__((ext_vector_type(2))) unsigned int u32x2;
typedef __attribute__((ext_vector_type(4))) unsigned int u32x4;

static __device__ __forceinline__ unsigned short f2bf(float f) {
    union { float f; unsigned u; } a; a.f = f;
    unsigned r = a.u + 0x7FFFu + ((a.u >> 16) & 1u);
    return (unsigned short)(r >> 16);
}

static __device__ __forceinline__ f32x2 pk_add(f32x2 a, f32x2 b) {
    f32x2 d; asm("v_pk_add_f32 %0, %1, %2" : "=v"(d) : "v"(a), "v"(b)); return d;
}
static __device__ __forceinline__ f32x2 pk_mul(f32x2 a, f32x2 b) {
    f32x2 d; asm("v_pk_mul_f32 %0, %1, %2" : "=v"(d) : "v"(a), "v"(b)); return d;
}
static __device__ __forceinline__ f32x2 pk_fma(f32x2 a, f32x2 b, f32x2 c) {
    f32x2 d; asm("v_pk_fma_f32 %0, %1, %2, %3" : "=v"(d) : "v"(a), "v"(b), "v"(c)); return d;
}
static __device__ __forceinline__ f32x2 pk_abs(f32x2 a) {
    u32x2 u = __builtin_bit_cast(u32x2, a);
    u &= 0x7FFFFFFFu;
    return __builtin_bit_cast(f32x2, u);
}
static __device__ __forceinline__ f32x2 bf2x(unsigned u) {
    f32x2 r;
    r.x = __uint_as_float(u << 16);
    r.y = __uint_as_float(u & 0xFFFF0000u);
    return r;
}

static __device__ __forceinline__ float red4_dpp(float p) {
    int v = __builtin_amdgcn_update_dpp(0, __builtin_bit_cast(int, p), 0xB1, 0xf, 0xf, true);
    p += __builtin_bit_cast(float, v);
    v = __builtin_amdgcn_update_dpp(0, __builtin_bit_cast(int, p), 0x4E, 0xf, 0xf, true);
    p += __builtin_bit_cast(float, v);
    return p;
}

#define SCB 256

// ---------------- K_prep: P1 edge-bucketing | convx | packw ----------------

__global__ __launch_bounds__(256) void k_prep(
    const int* __restrict__ srcp, const int* __restrict__ dstp,
    int* __restrict__ bcur, unsigned* __restrict__ ebuf, int E, int N,
    const float* __restrict__ X, ushort* __restrict__ Xb, int Mp,
    const float* __restrict__ W0, const float* __restrict__ W1, const float* __restrict__ W2,
    const float* __restrict__ W3, const float* __restrict__ W4, const float* __restrict__ W5,
    ushort* __restrict__ Wp, int nP1, int nCV)
{
    const int bx = blockIdx.x;
    const int tid = threadIdx.x;
    if (bx < nP1) {
        __shared__ int h[NBMAX];
        const int E2 = E + N;
        const int e0 = bx * P1CHUNK;
        const int e1 = min(e0 + P1CHUNK, E2);
        for (int t = tid; t < NBMAX; t += 256) h[t] = 0;
        __syncthreads();
        for (int e = e0 + tid; e < e1; e += 256) {
            int d = (e < E) ? dstp[e] : e - E;
            atomicAdd(&h[d >> 7], 1);
        }
        __syncthreads();
        for (int b = tid; b < NBMAX; b += 256) {
            int c = h[b];
            h[b] = c ? atomicAdd(&bcur[b], c) : 0;
        }
        __syncthreads();
        for (int e = e0 + tid; e < e1; e += 256) {
            int d  = (e < E) ? dstp[e] : e - E;
            int sc = (e < E) ? srcp[e] : e - E;
            int b = d >> 7;
            int pos = atomicAdd(&h[b], 1) & (CAP - 1);
            ebuf[(size_t)b * CAP + pos] = ((unsigned)sc << 7) | (unsigned)(d & 127);
        }
    } else if (bx < nP1 + nCV) {
        int idx = (bx - nP1) * 256 + tid;
        if (idx >= Mp * (D / 4)) return;
        ushort4 o;
        if (idx < N * (D / 4)) {
            float4 v = ((const float4*)X)[idx];
            o.x = f2bf(v.x); o.y = f2bf(v.y); o.z = f2bf(v.z); o.w = f2bf(v.w);
        } else {
            o = make_ushort4(0, 0, 0, 0);
        }
        ((ushort4*)Xb)[idx] = o;
    } else {
        int bid = bx - nP1 - nCV;
        int m = bid >> 6;
        int o = ((bid & 63) << 8) + tid;
        const float* W;
        if (m == 0) W = W0; else if (m == 1) W = W1; else if (m == 2) W = W2;
        else if (m == 3) W = W3; else if (m == 4) W = W4; else W = W5;
        int j  = o & 7;
        int l  = (o >> 3) & 63;
        int ct = (o >> 9) & 7;
        int kc = o >> 12;
        int k   = kc * 32 + ((l >> 4) << 3) + j;
        int col = (ct << 4) + (l & 15);
        Wp[m * 16384 + o] = f2bf(W[k * D + col]);
    }
}

// ---------------- P2a: per-bucket histogram -> deg (coalesced) + bucket totals ----------------

__global__ __launch_bounds__(256) void bhist_kernel(const unsigned* __restrict__ ebuf,
                                                    const int* __restrict__ bcur,
                                                    int* __restrict__ deg,
                                                    int* __restrict__ btot, int N) {
    const int b = blockIdx.x;
    const int base = b << 7;
    const int tid = threadIdx.x;
    __shared__ int h[128];
    __shared__ int t2[2];
    if (tid < 128) h[tid] = 0;
    __syncthreads();
    const int cnt = min(bcur[b], CAP);
    for (int k = tid; k < cnt; k += 256) {
        unsigned v = ebuf[(size_t)b * CAP + k];
        atomicAdd(&h[v & 127], 1);
    }
    __syncthreads();
    int v = (tid < 128) ? h[tid] : 0;
    if (tid < 128 && base + tid < N) deg[base + tid] = v;
    #pragma unroll
    for (int o = 32; o >= 1; o >>= 1) v += __shfl_xor(v, o);
    if (tid == 0)  t2[0] = v;
    if (tid == 64) t2[1] = v;
    __syncthreads();
    if (tid == 0) btot[b] = t2[0] + t2[1];
}

// ---------------- gemm body (bf16 A; RES stored bf16) ----------------

static __device__ __forceinline__ void gemm_body(
    int bxg, int seg, int tid,
    const ushort* __restrict__ Xb, const ushort* __restrict__ Wp,
    const float* __restrict__ bl, const float* __restrict__ br,
    ushort* __restrict__ XLb, ushort* __restrict__ XRb, ushort* __restrict__ RESb)
{
    const int l = tid & 63;
    const int wave = tid >> 6;
    const int wr = wave >> 1, wc = wave & 1;
    const int brow = bxg * 128 + wr * 64;
    const ushort* W = Wp + seg * 16384;

    f32x4 acc[4][4] = {};
    const int arow = brow + (l & 15);
    const int koff = (l >> 4) * 8;

    #pragma unroll
    for (int kc = 0; kc < 4; ++kc) {
        short8 A[4], B[4];
        #pragma unroll
        for (int at = 0; at < 4; ++at)
            A[at] = *(const short8*)&Xb[(size_t)(arow + at * 16) * D + kc * 32 + koff];
        #pragma unroll
        for (int ct = 0; ct < 4; ++ct) {
            int ctg = wc * 4 + ct;
            B[ct] = *(const short8*)&W[(((kc * 8 + ctg) * 64) + l) * 8];
        }
        #pragma unroll
        for (int at = 0; at < 4; ++at)
            #pragma unroll
            for (int ct = 0; ct < 4; ++ct)
                acc[at][ct] = __builtin_amdgcn_mfma_f32_16x16x32_bf16(A[at], B[ct], acc[at][ct], 0, 0, 0);
    }

    const int c = l & 15;
    const int r0 = (l >> 4) * 4;
    const float* bias = (seg == 0) ? bl : ((seg == 1) ? br : nullptr);
    #pragma unroll
    for (int ct = 0; ct < 4; ++ct) {
        int gcol = wc * 64 + ct * 16 + c;
        float bv = bias ? bias[gcol] : 0.f;
        #pragma unroll
        for (int at = 0; at < 4; ++at) {
            #pragma unroll
            for (int r = 0; r < 4; ++r) {
                int grow = brow + at * 16 + r0 + r;
                float v = acc[at][ct][r] + bv;
                size_t off = (size_t)grow * D + gcol;
                if (seg == 0)      XLb[off]  = f2bf(v);
                else if (seg == 1) XRb[off]  = f2bf(v);
                else               RESb[off] = f2bf(v);
            }
        }
    }
}

// ---------------- K_mid: P2b (off-from-btot + bucket-local scatter) | gemm0 ----------------

__global__ __launch_bounds__(256) void k_mid(
    const unsigned* __restrict__ ebuf, const int* __restrict__ bcur,
    const int* __restrict__ deg, const int* __restrict__ btot,
    int* __restrict__ off, int* __restrict__ csrc, int N, int NB, int nblk,
    const ushort* __restrict__ Xb, const ushort* __restrict__ Wp,
    const float* __restrict__ bl, const float* __restrict__ br,
    ushort* __restrict__ XLb, ushort* __restrict__ XRb, ushort* __restrict__ RESb)
{
    const int bx = blockIdx.x;
    if (bx < NB) {
        const int b = bx;
        const int base = b << 7;
        const int tid = threadIdx.x;
        __shared__ int cur[128];
        __shared__ int wsum[4];
        __shared__ int wtot[2];

        int acc = 0;
        for (int t = tid; t < b; t += 256) acc += btot[t];
        #pragma unroll
        for (int o = 32; o >= 1; o >>= 1) acc += __shfl_xor(acc, o);
        if ((tid & 63) == 0) wsum[tid >> 6] = acc;
        __syncthreads();
        const int B = wsum[0] + wsum[1] + wsum[2] + wsum[3];

        int dv = 0;
        if (tid < 128 && base + tid < N) dv = deg[base + tid];
        int incl = dv;
        if (tid < 128) {
            #pragma unroll
            for (int o = 1; o < 64; o <<= 1) {
                int u = __shfl_up(incl, o);
                if ((tid & 63) >= o) incl += u;
            }
        }
        if (tid == 63)  wtot[0] = incl;
        if (tid == 127) wtot[1] = incl;
        __syncthreads();
        if (tid < 128) {
            int add = (tid >= 64) ? wtot[0] : 0;
            int excl = B + add + incl - dv;
            cur[tid] = excl;
            if (base + tid < N) off[base + tid] = excl;
        }
        if (b == NB - 1 && tid == 0) off[N] = B + wtot[0] + wtot[1];
        __syncthreads();

        const int cnt = min(bcur[b], CAP);
        for (int k = tid; k < cnt; k += 256) {
            unsigned v = ebuf[(size_t)b * CAP + k];
            int p = atomicAdd(&cur[v & 127], 1);
            csrc[p] = v >> 7;
        }
    } else {
        int bid = bx - NB;
        int seg = bid / nblk;
        int bxg = bid - seg * nblk;
        gemm_body(bxg, seg, threadIdx.x, Xb, Wp, bl, br, XLb, XRb, RESb);
    }
}

__global__ __launch_bounds__(256) void gemm_mfma(
    const ushort* __restrict__ Xb, const ushort* __restrict__ Wp,
    const float* __restrict__ bl, const float* __restrict__ br,
    ushort* __restrict__ XLb, ushort* __restrict__ XRb, ushort* __restrict__ RESb)
{
    gemm_body(blockIdx.x, blockIdx.y, threadIdx.x, Xb, Wp, bl, br, XLb, XRb, RESb);
}

// ---------------- GATv2 aggregation + residual + LN + ReLU ----------------
// 4 nodes/wave, 16 lanes/node, lane owns 8 channels; packed-f32 math;
// 2-deep gather pipeline; TWO independent online-softmax streams (even/odd
// batches) to halve the serial softmax dependency chain; bf16 RES.

__global__ __launch_bounds__(256) void gat_node(
    const ushort* __restrict__ XLb, const ushort* __restrict__ XRb, const ushort* __restrict__ RESb,
    const float* __restrict__ att, const float* __restrict__ bias,
    const float* __restrict__ g, const float* __restrict__ be,
    const int* __restrict__ off, const int* __restrict__ csrc,
    float* __restrict__ OUTf, ushort* __restrict__ OUTb)
{
    const int l = threadIdx.x & 63;
    const int i = blockIdx.x * 16 + (threadIdx.x >> 6) * 4 + (l >> 4);
    const int f = (l & 15) * 8;
    const unsigned ibase = ((unsigned)i << 7) + f;
    const int lb = l & 48;

    f32x2 at06[4], at04[4];
    #pragma unroll
    for (int k = 0; k < 4; ++k) {
        float2 a = *(const float2*)&att[f + k * 2];
        f32x2 av; av.x = a.x; av.y = a.y;
        at06[k] = av * (0.6f * INV_LN2);
        at04[k] = av * (0.4f * INV_LN2);
    }

    u32x4 xru = __builtin_nontemporal_load((const u32x4*)&XRb[ibase]);
    f32x2 xr2[4];
    xr2[0] = bf2x(xru.x); xr2[1] = bf2x(xru.y); xr2[2] = bf2x(xru.z); xr2[3] = bf2x(xru.w);

    const int e0 = off[i], e1 = off[i + 1];
    const int len = e1 - e0;
    int mx = max(len, __shfl_xor(len, 16));
    mx = max(mx, __shfl_xor(mx, 32));

    // two independent online-softmax streams
    float mA = -1e30f, sA = 0.f;
    float mB = -1e30f, sB = 0.f;
    f32x2 aA[4] = {};
    f32x2 aB[4] = {};

    for (int c0 = 0; c0 < mx; c0 += 16) {
        int myj = __builtin_nontemporal_load(&csrc[min(e0 + c0 + (l & 15), e1 - 1)]);
        const int rem = mx - c0;
        const int nbb = min(4, (rem + 3) >> 2);
        const int kleft = len - c0;

        u32x4 u_[4];
        {
            int s0 = __shfl(myj, lb + 0);
            int s1 = __shfl(myj, lb + 1);
            int s2 = __shfl(myj, lb + 2);
            int s3 = __shfl(myj, lb + 3);
            u_[0] = *(const u32x4*)&XLb[((unsigned)s0 << 7) + f];
            u_[1] = *(const u32x4*)&XLb[((unsigned)s1 << 7) + f];
            u_[2] = *(const u32x4*)&XLb[((unsigned)s2 << 7) + f];
            u_[3] = *(const u32x4*)&XLb[((unsigned)s3 << 7) + f];
        }

        #pragma unroll
        for (int bb = 0; bb < 4; ++bb) {
            if (bb >= nbb) break;
            u32x4 uc[4];
            #pragma unroll
            for (int j = 0; j < 4; ++j) uc[j] = u_[j];
            if (bb + 1 < nbb) {
                int s0 = __shfl(myj, lb + (bb + 1) * 4 + 0);
                int s1 = __shfl(myj, lb + (bb + 1) * 4 + 1);
                int s2 = __shfl(myj, lb + (bb + 1) * 4 + 2);
                int s3 = __shfl(myj, lb + (bb + 1) * 4 + 3);
                u_[0] = *(const u32x4*)&XLb[((unsigned)s0 << 7) + f];
                u_[1] = *(const u32x4*)&XLb[((unsigned)s1 << 7) + f];
                u_[2] = *(const u32x4*)&XLb[((unsigned)s2 << 7) + f];
                u_[3] = *(const u32x4*)&XLb[((unsigned)s3 << 7) + f];
            }

            const int kb = kleft - bb * 4;
            f32x2 xp[4][4];
            float p[4];
            #pragma unroll
            for (int j = 0; j < 4; ++j) {
                xp[j][0] = bf2x(uc[j].x);
                xp[j][1] = bf2x(uc[j].y);
                xp[j][2] = bf2x(uc[j].z);
                xp[j][3] = bf2x(uc[j].w);
                f32x2 v0 = pk_add(xp[j][0], xr2[0]);
                f32x2 pj2 = pk_mul(v0, at06[0]);
                pj2 = pk_fma(pk_abs(v0), at04[0], pj2);
                #pragma unroll
                for (int k = 1; k < 4; ++k) {
                    f32x2 v = pk_add(xp[j][k], xr2[k]);
                    pj2 = pk_fma(v, at06[k], pj2);
                    pj2 = pk_fma(pk_abs(v), at04[k], pj2);
                }
                float pj = pj2.x + pj2.y;
                pj = red4_dpp(pj);
                p[j] = (j < kb) ? pj : -1e30f;
            }
            float m0 = (bb & 1) ? mB : mA;
            float s0v = (bb & 1) ? sB : sA;
            float pmax = fmaxf(fmaxf(p[0], p[1]), fmaxf(p[2], p[3]));
            float nm = fmaxf(m0, pmax);
            float so = exp2f(m0 - nm);
            float w0 = exp2f(p[0] - nm), w1 = exp2f(p[1] - nm);
            float w2 = exp2f(p[2] - nm), w3 = exp2f(p[3] - nm);
            // explicit mask (guards the all-padded-batch case where m0 == pmax == -1e30)
            w0 = (0 < kb) ? w0 : 0.f;
            w1 = (1 < kb) ? w1 : 0.f;
            w2 = (2 < kb) ? w2 : 0.f;
            w3 = (3 < kb) ? w3 : 0.f;
            float sn = s0v * so + ((w0 + w1) + (w2 + w3));
            f32x2 so2; so2.x = so; so2.y = so;
            f32x2 w02; w02.x = w0; w02.y = w0;
            f32x2 w12; w12.x = w1; w12.y = w1;
            f32x2 w22; w22.x = w2; w22.y = w2;
            f32x2 w32; w32.x = w3; w32.y = w3;
            if (bb & 1) {
                #pragma unroll
                for (int k = 0; k < 4; ++k) {
                    f32x2 t = pk_mul(xp[0][k], w02);
                    t = pk_fma(xp[1][k], w12, t);
                    t = pk_fma(xp[2][k], w22, t);
                    t = pk_fma(xp[3][k], w32, t);
                    aB[k] = pk_fma(aB[k], so2, t);
                }
                mB = nm; sB = sn;
            } else {
                #pragma unroll
                for (int k = 0; k < 4; ++k) {
                    f32x2 t = pk_mul(xp[0][k], w02);
                    t = pk_fma(xp[1][k], w12, t);
                    t = pk_fma(xp[2][k], w22, t);
                    t = pk_fma(xp[3][k], w32, t);
                    aA[k] = pk_fma(aA[k], so2, t);
                }
                mA = nm; sA = sn;
            }
        }
    }

    // merge the two streams
    float nmv = fmaxf(mA, mB);
    float soA = exp2f(mA - nmv);
    float soB = exp2f(mB - nmv);
    float s = sA * soA + sB * soB;
    f32x2 soA2; soA2.x = soA; soA2.y = soA;
    f32x2 soB2; soB2.x = soB; soB2.y = soB;
    f32x2 a2[4];
    #pragma unroll
    for (int k = 0; k < 4; ++k)
        a2[k] = pk_add(pk_mul(aA[k], soA2), pk_mul(aB[k], soB2));

    u32x4 ru = __builtin_nontemporal_load((const u32x4*)&RESb[ibase]);
    f32x2 rs2[4];
    rs2[0] = bf2x(ru.x); rs2[1] = bf2x(ru.y); rs2[2] = bf2x(ru.z); rs2[3] = bf2x(ru.w);
    const float4 biA = *(const float4*)&bias[f];
    const float4 biB = *(const float4*)&bias[f + 4];
    float inv = 1.f / s;
    float r0 = a2[0].x * inv + rs2[0].x + biA.x;
    float r1 = a2[0].y * inv + rs2[0].y + biA.y;
    float r2 = a2[1].x * inv + rs2[1].x + biA.z;
    float r3 = a2[1].y * inv + rs2[1].y + biA.w;
    float r4 = a2[2].x * inv + rs2[2].x + biB.x;
    float r5 = a2[2].y * inv + rs2[2].y + biB.y;
    float r6 = a2[3].x * inv + rs2[3].x + biB.z;
    float r7 = a2[3].y * inv + rs2[3].y + biB.w;

    float sum = ((r0 + r1) + (r2 + r3)) + ((r4 + r5) + (r6 + r7));
    float sq  = ((r0 * r0 + r1 * r1) + (r2 * r2 + r3 * r3))
              + ((r4 * r4 + r5 * r5) + (r6 * r6 + r7 * r7));
    #pragma unroll
    for (int o = 8; o >= 1; o >>= 1) {
        sum += __shfl_xor(sum, o);
        sq  += __shfl_xor(sq, o);
    }
    float mu  = sum * (1.f / 128.f);
    float var = sq * (1.f / 128.f) - mu * mu;
    float isd = rsqrtf(var + LN_EPS);
    const float4 gvA = *(const float4*)&g[f];
    const float4 gvB = *(const float4*)&g[f + 4];
    const float4 bvA = *(const float4*)&be[f];
    const float4 bvB = *(const float4*)&be[f + 4];
    float o0 = fmaxf((r0 - mu) * isd * gvA.x + bvA.x, 0.f);
    float o1 = fmaxf((r1 - mu) * isd * gvA.y + bvA.y, 0.f);
    float o2 = fmaxf((r2 - mu) * isd * gvA.z + bvA.z, 0.f);
    float o3 = fmaxf((r3 - mu) * isd * gvA.w + bvA.w, 0.f);
    float o4 = fmaxf((r4 - mu) * isd * gvB.x + bvB.x, 0.f);
    float o5 = fmaxf((r5 - mu) * isd * gvB.y + bvB.y, 0.f);
    float o6 = fmaxf((r6 - mu) * isd * gvB.z + bvB.z, 0.f);
    float o7 = fmaxf((r7 - mu) * isd * gvB.w + bvB.w, 0.f);

    if (OUTb) {
        ushort8 ob;
        ob[0] = f2bf(o0); ob[1] = f2bf(o1); ob[2] = f2bf(o2); ob[3] = f2bf(o3);
        ob[4] = f2bf(o4); ob[5] = f2bf(o5); ob[6] = f2bf(o6); ob[7] = f2bf(o7);
        __builtin_nontemporal_store(ob, (ushort8*)&OUTb[ibase]);
    } else {
        f32x4 oA; oA.x = o0; oA.y = o1; oA.z = o2; oA.w = o3;
        f32x4 oB; oB.x = o4; oB.y = o5; oB.z = o6; oB.w = o7;
        __builtin_nontemporal_store(oA, (f32x4*)&OUTf[ibase]);
        __builtin_nontemporal_store(oB, (f32x4*)&OUTf[ibase + 4]);
    }
}

// ---------------- launch ----------------

extern "C" void kernel_launch(void* const* d_in, const int* in_sizes, int n_in,
                              void* d_out, int out_size, void* d_ws, size_t ws_size,
                              hipStream_t stream)
{
    const float* x    = (const float*)d_in[0];
    const int*   ei   = (const int*)d_in[1];
    const float* Wl0  = (const float*)d_in[2];
    const float* bl0  = (const float*)d_in[3];
    const float* Wr0  = (const float*)d_in[4];
    const float* br0  = (const float*)d_in[5];
    const float* att0 = (const float*)d_in[6];
    const float* Wres0= (const float*)d_in[7];
    const float* bias0= (const float*)d_in[8];
    const float* g0   = (const float*)d_in[9];
    const float* be0  = (const float*)d_in[10];
    const float* Wl1  = (const float*)d_in[11];
    const float* bl1  = (const float*)d_in[12];
    const float* Wr1  = (const float*)d_in[13];
    const float* br1  = (const float*)d_in[14];
    const float* att1 = (const float*)d_in[15];
    const float* Wres1= (const float*)d_in[16];
    const float* bias1= (const float*)d_in[17];
    const float* g1   = (const float*)d_in[18];
    const float* be1  = (const float*)d_in[19];

    const int N  = in_sizes[0] / D;
    const int E  = in_sizes[1] / 2;
    const int E2 = E + N;
    const int nblk = (N + 127) / 128;   // = NB buckets
    const int Mp = nblk * 128;
    const int NB = nblk;

    char* w = (char*)d_ws;
    ushort* Xb   = (ushort*)w; w += (size_t)Mp * D * 2;
    ushort* Hb   = (ushort*)w; w += (size_t)Mp * D * 2;
    ushort* XLb  = (ushort*)w; w += (size_t)Mp * D * 2;
    ushort* XRb  = (ushort*)w; w += (size_t)Mp * D * 2;
    ushort* RESb = (ushort*)w; w += (size_t)Mp * D * 2;
    ushort* Wp   = (ushort*)w; w += (size_t)6 * 16384 * 2;
    int* deg     = (int*)w; w += (size_t)N * 4;
    int* off     = (int*)w; w += (size_t)(N + 1) * 4;
    int* bcur    = (int*)w; w += (size_t)NBMAX * 4;
    int* btot    = (int*)w; w += (size_t)NBMAX * 4;
    unsigned* ebuf = (unsigned*)w; w += (size_t)NB * CAP * 4;
    int* csrc    = (int*)w; w += (size_t)E2 * 4;

    const int* srcp = ei;
    const int* dstp = ei + E;

    const int nP1 = (E2 + P1CHUNK - 1) / P1CHUNK;
    const int nCV = (Mp * (D / 4) + 255) / 256;
    const int nPW = 6 * 64;
    const int nGM = nblk * 3;

    hipMemsetAsync(bcur, 0, (size_t)NBMAX * 4, stream);
    k_prep<<<nP1 + nCV + nPW, 256, 0, stream>>>(srcp, dstp, bcur, ebuf, E, N,
                                                x, Xb, Mp,
                                                Wl0, Wr0, Wres0, Wl1, Wr1, Wres1,
                                                Wp, nP1, nCV);
    bhist_kernel<<<NB, 256, 0, stream>>>(ebuf, bcur, deg, btot, N);

    k_mid<<<NB + nGM, 256, 0, stream>>>(ebuf, bcur, deg, btot, off, csrc, N, NB, nblk,
                                        Xb, Wp, bl0, br0, XLb, XRb, RESb);

    const int gatg = N / 16;
    dim3 ggrid(nblk, 3);

    gat_node<<<gatg, 256, 0, stream>>>(XLb, XRb, RESb, att0, bias0, g0, be0, off, csrc, nullptr, Hb);
    gemm_mfma<<<ggrid, 256, 0, stream>>>(Hb, Wp + 3 * 16384, bl1, br1, XLb, XRb, RESb);
    gat_node<<<gatg, 256, 0, stream>>>(XLb, XRb, RESb, att1, bias1, g1, be1, off, csrc, (float*)d_out, nullptr);
}

// Round 18
// 176.991 us; speedup vs baseline: 1.0959x; 1.0461x over previous
//
#include <hip/hip_runtime.h>
#include <math.h>

#define D 128
#define LRELU 0.2f
#define LN_EPS 1e-5f
#define INV_LN2 1.4426950408889634f

#define NBMAX 512        // bucket table (NB = ceil(N/128) <= 512)
#define CAP 4096         // slots per bucket (mean fill ~2200)
#define P1CHUNK 8192     // edges per P1 block

typedef __attribute__((ext_vector_type(8))) short short8;
typedef __attribute__((ext_vector_type(8))) unsigned short ushort8;
typedef __attribute__((ext_vector_type(4))) float f32x4;
typedef __attribute__((ext_vector_type(2))) float f32x2;
typedef __attribute__((ext_vector_type(2))) unsigned int u32x2;
typedef __attribute__((ext_vector_type(4))) unsigned int u32x4;

static __device__ __forceinline__ unsigned short f2bf(float f) {
    union { float f; unsigned u; } a; a.f = f;
    unsigned r = a.u + 0x7FFFu + ((a.u >> 16) & 1u);
    return (unsigned short)(r >> 16);
}

static __device__ __forceinline__ f32x2 pk_add(f32x2 a, f32x2 b) {
    f32x2 d; asm("v_pk_add_f32 %0, %1, %2" : "=v"(d) : "v"(a), "v"(b)); return d;
}
static __device__ __forceinline__ f32x2 pk_mul(f32x2 a, f32x2 b) {
    f32x2 d; asm("v_pk_mul_f32 %0, %1, %2" : "=v"(d) : "v"(a), "v"(b)); return d;
}
static __device__ __forceinline__ f32x2 pk_fma(f32x2 a, f32x2 b, f32x2 c) {
    f32x2 d; asm("v_pk_fma_f32 %0, %1, %2, %3" : "=v"(d) : "v"(a), "v"(b), "v"(c)); return d;
}
static __device__ __forceinline__ f32x2 pk_abs(f32x2 a) {
    u32x2 u = __builtin_bit_cast(u32x2, a);
    u &= 0x7FFFFFFFu;
    return __builtin_bit_cast(f32x2, u);
}
static __device__ __forceinline__ f32x2 bf2x(unsigned u) {
    f32x2 r;
    r.x = __uint_as_float(u << 16);
    r.y = __uint_as_float(u & 0xFFFF0000u);
    return r;
}

static __device__ __forceinline__ float red4_dpp(float p) {
    int v = __builtin_amdgcn_update_dpp(0, __builtin_bit_cast(int, p), 0xB1, 0xf, 0xf, true);
    p += __builtin_bit_cast(float, v);
    v = __builtin_amdgcn_update_dpp(0, __builtin_bit_cast(int, p), 0x4E, 0xf, 0xf, true);
    p += __builtin_bit_cast(float, v);
    return p;
}

// ---------------- K_prep: P1 edge-bucketing | convx | packw ----------------

__global__ __launch_bounds__(256) void k_prep(
    const int* __restrict__ srcp, const int* __restrict__ dstp,
    int* __restrict__ bcur, unsigned* __restrict__ ebuf, int E, int N,
    const float* __restrict__ X, ushort* __restrict__ Xb, int Mp,
    const float* __restrict__ W0, const float* __restrict__ W1, const float* __restrict__ W2,
    const float* __restrict__ W3, const float* __restrict__ W4, const float* __restrict__ W5,
    ushort* __restrict__ Wp, int nP1, int nCV)
{
    const int bx = blockIdx.x;
    const int tid = threadIdx.x;
    if (bx < nP1) {
        __shared__ int h[NBMAX];
        const int E2 = E + N;
        const int e0 = bx * P1CHUNK;
        const int e1 = min(e0 + P1CHUNK, E2);
        for (int t = tid; t < NBMAX; t += 256) h[t] = 0;
        __syncthreads();
        for (int e = e0 + tid; e < e1; e += 256) {
            int d = (e < E) ? dstp[e] : e - E;
            atomicAdd(&h[d >> 7], 1);
        }
        __syncthreads();
        for (int b = tid; b < NBMAX; b += 256) {
            int c = h[b];
            h[b] = c ? atomicAdd(&bcur[b], c) : 0;
        }
        __syncthreads();
        for (int e = e0 + tid; e < e1; e += 256) {
            int d  = (e < E) ? dstp[e] : e - E;
            int sc = (e < E) ? srcp[e] : e - E;
            int b = d >> 7;
            int pos = atomicAdd(&h[b], 1) & (CAP - 1);
            ebuf[(size_t)b * CAP + pos] = ((unsigned)sc << 7) | (unsigned)(d & 127);
        }
    } else if (bx < nP1 + nCV) {
        int idx = (bx - nP1) * 256 + tid;
        if (idx >= Mp * (D / 4)) return;
        ushort4 o;
        if (idx < N * (D / 4)) {
            float4 v = ((const float4*)X)[idx];
            o.x = f2bf(v.x); o.y = f2bf(v.y); o.z = f2bf(v.z); o.w = f2bf(v.w);
        } else {
            o = make_ushort4(0, 0, 0, 0);
        }
        ((ushort4*)Xb)[idx] = o;
    } else {
        int bid = bx - nP1 - nCV;
        int m = bid >> 6;
        int o = ((bid & 63) << 8) + tid;
        const float* W;
        if (m == 0) W = W0; else if (m == 1) W = W1; else if (m == 2) W = W2;
        else if (m == 3) W = W3; else if (m == 4) W = W4; else W = W5;
        int j  = o & 7;
        int l  = (o >> 3) & 63;
        int ct = (o >> 9) & 7;
        int kc = o >> 12;
        int k   = kc * 32 + ((l >> 4) << 3) + j;
        int col = (ct << 4) + (l & 15);
        Wp[m * 16384 + o] = f2bf(W[k * D + col]);
    }
}

// ---------------- gemm body (bf16 A; RES stored bf16) ----------------

static __device__ __forceinline__ void gemm_body(
    int bxg, int seg, int tid,
    const ushort* __restrict__ Xb, const ushort* __restrict__ Wp,
    const float* __restrict__ bl, const float* __restrict__ br,
    ushort* __restrict__ XLb, ushort* __restrict__ XRb, ushort* __restrict__ RESb)
{
    const int l = tid & 63;
    const int wave = tid >> 6;
    const int wr = wave >> 1, wc = wave & 1;
    const int brow = bxg * 128 + wr * 64;
    const ushort* W = Wp + seg * 16384;

    f32x4 acc[4][4] = {};
    const int arow = brow + (l & 15);
    const int koff = (l >> 4) * 8;

    #pragma unroll
    for (int kc = 0; kc < 4; ++kc) {
        short8 A[4], B[4];
        #pragma unroll
        for (int at = 0; at < 4; ++at)
            A[at] = *(const short8*)&Xb[(size_t)(arow + at * 16) * D + kc * 32 + koff];
        #pragma unroll
        for (int ct = 0; ct < 4; ++ct) {
            int ctg = wc * 4 + ct;
            B[ct] = *(const short8*)&W[(((kc * 8 + ctg) * 64) + l) * 8];
        }
        #pragma unroll
        for (int at = 0; at < 4; ++at)
            #pragma unroll
            for (int ct = 0; ct < 4; ++ct)
                acc[at][ct] = __builtin_amdgcn_mfma_f32_16x16x32_bf16(A[at], B[ct], acc[at][ct], 0, 0, 0);
    }

    const int c = l & 15;
    const int r0 = (l >> 4) * 4;
    const float* bias = (seg == 0) ? bl : ((seg == 1) ? br : nullptr);
    #pragma unroll
    for (int ct = 0; ct < 4; ++ct) {
        int gcol = wc * 64 + ct * 16 + c;
        float bv = bias ? bias[gcol] : 0.f;
        #pragma unroll
        for (int at = 0; at < 4; ++at) {
            #pragma unroll
            for (int r = 0; r < 4; ++r) {
                int grow = brow + at * 16 + r0 + r;
                float v = acc[at][ct][r] + bv;
                size_t off = (size_t)grow * D + gcol;
                if (seg == 0)      XLb[off]  = f2bf(v);
                else if (seg == 1) XRb[off]  = f2bf(v);
                else               RESb[off] = f2bf(v);
            }
        }
    }
}

// ---------------- K_mid: P2b (hist+off+scatter from ebuf, 2-pass) | gemm0 ----------------

__global__ __launch_bounds__(256) void k_mid(
    const unsigned* __restrict__ ebuf, const int* __restrict__ bcur,
    int* __restrict__ off, int* __restrict__ csrc, int N, int NB, int nblk,
    const ushort* __restrict__ Xb, const ushort* __restrict__ Wp,
    const float* __restrict__ bl, const float* __restrict__ br,
    ushort* __restrict__ XLb, ushort* __restrict__ XRb, ushort* __restrict__ RESb)
{
    const int bx = blockIdx.x;
    if (bx < NB) {
        const int b = bx;
        const int base = b << 7;
        const int tid = threadIdx.x;
        const int cntN = min(128, N - base);
        __shared__ int h[128];
        __shared__ int cur[128];
        __shared__ int wsum[4];
        __shared__ int wtot[2];

        // global base offset B = sum bcur[0..b)
        int acc = 0;
        for (int t = tid; t < b; t += 256) acc += bcur[t];
        #pragma unroll
        for (int o = 32; o >= 1; o >>= 1) acc += __shfl_xor(acc, o);
        if ((tid & 63) == 0) wsum[tid >> 6] = acc;
        if (tid < 128) h[tid] = 0;
        __syncthreads();
        const int B = wsum[0] + wsum[1] + wsum[2] + wsum[3];

        // pass 1: per-node degree histogram
        const int cnt = min(bcur[b], CAP);
        for (int k = tid; k < cnt; k += 256) {
            unsigned v = ebuf[(size_t)b * CAP + k];
            atomicAdd(&h[v & 127], 1);
        }
        __syncthreads();

        // local exclusive scan -> off, cur
        int dv = (tid < 128) ? h[tid] : 0;
        int incl = dv;
        if (tid < 128) {
            #pragma unroll
            for (int o = 1; o < 64; o <<= 1) {
                int u = __shfl_up(incl, o);
                if ((tid & 63) >= o) incl += u;
            }
        }
        if (tid == 63)  wtot[0] = incl;
        if (tid == 127) wtot[1] = incl;
        __syncthreads();
        if (tid < 128) {
            int add = (tid >= 64) ? wtot[0] : 0;
            int excl = B + add + incl - dv;
            cur[tid] = excl;
            if (tid < cntN) off[base + tid] = excl;
        }
        if (b == NB - 1 && tid == 0) off[N] = B + wtot[0] + wtot[1];
        __syncthreads();

        // pass 2: bucket-local scatter
        for (int k = tid; k < cnt; k += 256) {
            unsigned v = ebuf[(size_t)b * CAP + k];
            int p = atomicAdd(&cur[v & 127], 1);
            csrc[p] = v >> 7;
        }
    } else {
        int bid = bx - NB;
        int seg = bid / nblk;
        int bxg = bid - seg * nblk;
        gemm_body(bxg, seg, threadIdx.x, Xb, Wp, bl, br, XLb, XRb, RESb);
    }
}

__global__ __launch_bounds__(256) void gemm_mfma(
    const ushort* __restrict__ Xb, const ushort* __restrict__ Wp,
    const float* __restrict__ bl, const float* __restrict__ br,
    ushort* __restrict__ XLb, ushort* __restrict__ XRb, ushort* __restrict__ RESb)
{
    gemm_body(blockIdx.x, blockIdx.y, threadIdx.x, Xb, Wp, bl, br, XLb, XRb, RESb);
}

// ---------------- GATv2 aggregation + residual + LN + ReLU ----------------
// 4 nodes/wave (natural order), 16 lanes/node, lane owns 8 channels;
// packed-f32 math; 2-deep gather pipeline; single-stream online softmax;
// bf16 RES; NT hints on streamed operands.

__global__ __launch_bounds__(256) void gat_node(
    const ushort* __restrict__ XLb, const ushort* __restrict__ XRb, const ushort* __restrict__ RESb,
    const float* __restrict__ att, const float* __restrict__ bias,
    const float* __restrict__ g, const float* __restrict__ be,
    const int* __restrict__ off, const int* __restrict__ csrc,
    float* __restrict__ OUTf, ushort* __restrict__ OUTb)
{
    const int l = threadIdx.x & 63;
    const int i = blockIdx.x * 16 + (threadIdx.x >> 6) * 4 + (l >> 4);
    const int f = (l & 15) * 8;
    const unsigned ibase = ((unsigned)i << 7) + f;
    const int lb = l & 48;

    f32x2 at06[4], at04[4];
    #pragma unroll
    for (int k = 0; k < 4; ++k) {
        float2 a = *(const float2*)&att[f + k * 2];
        f32x2 av; av.x = a.x; av.y = a.y;
        at06[k] = av * (0.6f * INV_LN2);
        at04[k] = av * (0.4f * INV_LN2);
    }

    u32x4 xru = __builtin_nontemporal_load((const u32x4*)&XRb[ibase]);
    f32x2 xr2[4];
    xr2[0] = bf2x(xru.x); xr2[1] = bf2x(xru.y); xr2[2] = bf2x(xru.z); xr2[3] = bf2x(xru.w);

    const int e0 = off[i], e1 = off[i + 1];
    const int len = e1 - e0;
    int mx = max(len, __shfl_xor(len, 16));
    mx = max(mx, __shfl_xor(mx, 32));

    float m = -1e30f, s = 0.f;
    f32x2 a2[4] = {};

    for (int c0 = 0; c0 < mx; c0 += 16) {
        int myj = __builtin_nontemporal_load(&csrc[min(e0 + c0 + (l & 15), e1 - 1)]);
        const int rem = mx - c0;
        const int nbb = min(4, (rem + 3) >> 2);
        const int kleft = len - c0;

        u32x4 u_[4];
        {
            int s0 = __shfl(myj, lb + 0);
            int s1 = __shfl(myj, lb + 1);
            int s2 = __shfl(myj, lb + 2);
            int s3 = __shfl(myj, lb + 3);
            u_[0] = *(const u32x4*)&XLb[((unsigned)s0 << 7) + f];
            u_[1] = *(const u32x4*)&XLb[((unsigned)s1 << 7) + f];
            u_[2] = *(const u32x4*)&XLb[((unsigned)s2 << 7) + f];
            u_[3] = *(const u32x4*)&XLb[((unsigned)s3 << 7) + f];
        }

        #pragma unroll
        for (int bb = 0; bb < 4; ++bb) {
            if (bb >= nbb) break;
            u32x4 uc[4];
            #pragma unroll
            for (int j = 0; j < 4; ++j) uc[j] = u_[j];
            if (bb + 1 < nbb) {
                int s0 = __shfl(myj, lb + (bb + 1) * 4 + 0);
                int s1 = __shfl(myj, lb + (bb + 1) * 4 + 1);
                int s2 = __shfl(myj, lb + (bb + 1) * 4 + 2);
                int s3 = __shfl(myj, lb + (bb + 1) * 4 + 3);
                u_[0] = *(const u32x4*)&XLb[((unsigned)s0 << 7) + f];
                u_[1] = *(const u32x4*)&XLb[((unsigned)s1 << 7) + f];
                u_[2] = *(const u32x4*)&XLb[((unsigned)s2 << 7) + f];
                u_[3] = *(const u32x4*)&XLb[((unsigned)s3 << 7) + f];
            }

            const int kb = kleft - bb * 4;
            f32x2 xp[4][4];
            float p[4];
            #pragma unroll
            for (int j = 0; j < 4; ++j) {
                xp[j][0] = bf2x(uc[j].x);
                xp[j][1] = bf2x(uc[j].y);
                xp[j][2] = bf2x(uc[j].z);
                xp[j][3] = bf2x(uc[j].w);
                f32x2 v0 = pk_add(xp[j][0], xr2[0]);
                f32x2 pj2 = pk_mul(v0, at06[0]);
                pj2 = pk_fma(pk_abs(v0), at04[0], pj2);
                #pragma unroll
                for (int k = 1; k < 4; ++k) {
                    f32x2 v = pk_add(xp[j][k], xr2[k]);
                    pj2 = pk_fma(v, at06[k], pj2);
                    pj2 = pk_fma(pk_abs(v), at04[k], pj2);
                }
                float pj = pj2.x + pj2.y;
                pj = red4_dpp(pj);
                p[j] = (j < kb) ? pj : -1e30f;
            }
            float pmax = fmaxf(fmaxf(p[0], p[1]), fmaxf(p[2], p[3]));
            float nm = fmaxf(m, pmax);
            float so = exp2f(m - nm);
            float w0 = exp2f(p[0] - nm), w1 = exp2f(p[1] - nm);
            float w2 = exp2f(p[2] - nm), w3 = exp2f(p[3] - nm);
            s = s * so + ((w0 + w1) + (w2 + w3));
            f32x2 so2; so2.x = so; so2.y = so;
            f32x2 w02; w02.x = w0; w02.y = w0;
            f32x2 w12; w12.x = w1; w12.y = w1;
            f32x2 w22; w22.x = w2; w22.y = w2;
            f32x2 w32; w32.x = w3; w32.y = w3;
            #pragma unroll
            for (int k = 0; k < 4; ++k) {
                f32x2 t = pk_mul(xp[0][k], w02);
                t = pk_fma(xp[1][k], w12, t);
                t = pk_fma(xp[2][k], w22, t);
                t = pk_fma(xp[3][k], w32, t);
                a2[k] = pk_fma(a2[k], so2, t);
            }
            m = nm;
        }
    }

    u32x4 ru = __builtin_nontemporal_load((const u32x4*)&RESb[ibase]);
    f32x2 rs2[4];
    rs2[0] = bf2x(ru.x); rs2[1] = bf2x(ru.y); rs2[2] = bf2x(ru.z); rs2[3] = bf2x(ru.w);
    const float4 biA = *(const float4*)&bias[f];
    const float4 biB = *(const float4*)&bias[f + 4];
    float inv = 1.f / s;
    float r0 = a2[0].x * inv + rs2[0].x + biA.x;
    float r1 = a2[0].y * inv + rs2[0].y + biA.y;
    float r2 = a2[1].x * inv + rs2[1].x + biA.z;
    float r3 = a2[1].y * inv + rs2[1].y + biA.w;
    float r4 = a2[2].x * inv + rs2[2].x + biB.x;
    float r5 = a2[2].y * inv + rs2[2].y + biB.y;
    float r6 = a2[3].x * inv + rs2[3].x + biB.z;
    float r7 = a2[3].y * inv + rs2[3].y + biB.w;

    float sum = ((r0 + r1) + (r2 + r3)) + ((r4 + r5) + (r6 + r7));
    float sq  = ((r0 * r0 + r1 * r1) + (r2 * r2 + r3 * r3))
              + ((r4 * r4 + r5 * r5) + (r6 * r6 + r7 * r7));
    #pragma unroll
    for (int o = 8; o >= 1; o >>= 1) {
        sum += __shfl_xor(sum, o);
        sq  += __shfl_xor(sq, o);
    }
    float mu  = sum * (1.f / 128.f);
    float var = sq * (1.f / 128.f) - mu * mu;
    float isd = rsqrtf(var + LN_EPS);
    const float4 gvA = *(const float4*)&g[f];
    const float4 gvB = *(const float4*)&g[f + 4];
    const float4 bvA = *(const float4*)&be[f];
    const float4 bvB = *(const float4*)&be[f + 4];
    float o0 = fmaxf((r0 - mu) * isd * gvA.x + bvA.x, 0.f);
    float o1 = fmaxf((r1 - mu) * isd * gvA.y + bvA.y, 0.f);
    float o2 = fmaxf((r2 - mu) * isd * gvA.z + bvA.z, 0.f);
    float o3 = fmaxf((r3 - mu) * isd * gvA.w + bvA.w, 0.f);
    float o4 = fmaxf((r4 - mu) * isd * gvB.x + bvB.x, 0.f);
    float o5 = fmaxf((r5 - mu) * isd * gvB.y + bvB.y, 0.f);
    float o6 = fmaxf((r6 - mu) * isd * gvB.z + bvB.z, 0.f);
    float o7 = fmaxf((r7 - mu) * isd * gvB.w + bvB.w, 0.f);

    if (OUTb) {
        ushort8 ob;
        ob[0] = f2bf(o0); ob[1] = f2bf(o1); ob[2] = f2bf(o2); ob[3] = f2bf(o3);
        ob[4] = f2bf(o4); ob[5] = f2bf(o5); ob[6] = f2bf(o6); ob[7] = f2bf(o7);
        __builtin_nontemporal_store(ob, (ushort8*)&OUTb[ibase]);
    } else {
        f32x4 oA; oA.x = o0; oA.y = o1; oA.z = o2; oA.w = o3;
        f32x4 oB; oB.x = o4; oB.y = o5; oB.z = o6; oB.w = o7;
        __builtin_nontemporal_store(oA, (f32x4*)&OUTf[ibase]);
        __builtin_nontemporal_store(oB, (f32x4*)&OUTf[ibase + 4]);
    }
}

// ---------------- launch ----------------

extern "C" void kernel_launch(void* const* d_in, const int* in_sizes, int n_in,
                              void* d_out, int out_size, void* d_ws, size_t ws_size,
                              hipStream_t stream)
{
    const float* x    = (const float*)d_in[0];
    const int*   ei   = (const int*)d_in[1];
    const float* Wl0  = (const float*)d_in[2];
    const float* bl0  = (const float*)d_in[3];
    const float* Wr0  = (const float*)d_in[4];
    const float* br0  = (const float*)d_in[5];
    const float* att0 = (const float*)d_in[6];
    const float* Wres0= (const float*)d_in[7];
    const float* bias0= (const float*)d_in[8];
    const float* g0   = (const float*)d_in[9];
    const float* be0  = (const float*)d_in[10];
    const float* Wl1  = (const float*)d_in[11];
    const float* bl1  = (const float*)d_in[12];
    const float* Wr1  = (const float*)d_in[13];
    const float* br1  = (const float*)d_in[14];
    const float* att1 = (const float*)d_in[15];
    const float* Wres1= (const float*)d_in[16];
    const float* bias1= (const float*)d_in[17];
    const float* g1   = (const float*)d_in[18];
    const float* be1  = (const float*)d_in[19];

    const int N  = in_sizes[0] / D;
    const int E  = in_sizes[1] / 2;
    const int E2 = E + N;
    const int nblk = (N + 127) / 128;   // = NB buckets
    const int Mp = nblk * 128;
    const int NB = nblk;

    char* w = (char*)d_ws;
    ushort* Xb   = (ushort*)w; w += (size_t)Mp * D * 2;
    ushort* Hb   = (ushort*)w; w += (size_t)Mp * D * 2;
    ushort* XLb  = (ushort*)w; w += (size_t)Mp * D * 2;
    ushort* XRb  = (ushort*)w; w += (size_t)Mp * D * 2;
    ushort* RESb = (ushort*)w; w += (size_t)Mp * D * 2;
    ushort* Wp   = (ushort*)w; w += (size_t)6 * 16384 * 2;
    int* off     = (int*)w; w += (size_t)(N + 1) * 4;
    int* bcur    = (int*)w; w += (size_t)NBMAX * 4;
    unsigned* ebuf = (unsigned*)w; w += (size_t)NB * CAP * 4;
    int* csrc    = (int*)w; w += (size_t)E2 * 4;

    const int* srcp = ei;
    const int* dstp = ei + E;

    const int nP1 = (E2 + P1CHUNK - 1) / P1CHUNK;
    const int nCV = (Mp * (D / 4) + 255) / 256;
    const int nPW = 6 * 64;
    const int nGM = nblk * 3;

    hipMemsetAsync(bcur, 0, (size_t)NBMAX * 4, stream);
    k_prep<<<nP1 + nCV + nPW, 256, 0, stream>>>(srcp, dstp, bcur, ebuf, E, N,
                                                x, Xb, Mp,
                                                Wl0, Wr0, Wres0, Wl1, Wr1, Wres1,
                                                Wp, nP1, nCV);

    // P2b (hist+off+scatter) + gemm layer-0 fused
    k_mid<<<NB + nGM, 256, 0, stream>>>(ebuf, bcur, off, csrc, N, NB, nblk,
                                        Xb, Wp, bl0, br0, XLb, XRb, RESb);

    const int gatg = N / 16;
    dim3 ggrid(nblk, 3);

    gat_node<<<gatg, 256, 0, stream>>>(XLb, XRb, RESb, att0, bias0, g0, be0, off, csrc, nullptr, Hb);
    gemm_mfma<<<ggrid, 256, 0, stream>>>(Hb, Wp + 3 * 16384, bl1, br1, XLb, XRb, RESb);
    gat_node<<<gatg, 256, 0, stream>>>(XLb, XRb, RESb, att1, bias1, g1, be1, off, csrc, (float*)d_out, nullptr);
}